// Round 14
// baseline (155.697 us; speedup 1.0000x reference)
//
#include <hip/hip_runtime.h>
#include <math.h>

#define BB 4
#define CC 256
#define NHEAD 4
#define DH 32
#define NN 4096
#define HID 128

typedef _Float16 f16;
typedef _Float16 f16x8 __attribute__((ext_vector_type(8)));
typedef _Float16 f16x4 __attribute__((ext_vector_type(4)));
typedef float f32x4 __attribute__((ext_vector_type(4)));
typedef unsigned int u32x4 __attribute__((ext_vector_type(4)));

#define QPRESCALE 14.42695041f
#define NSHIFT 14.42695041f

#if __has_builtin(__builtin_amdgcn_exp2f)
#define EXP2F(x) __builtin_amdgcn_exp2f(x)
#else
#define EXP2F(x) __expf((x)*0.6931471805599453f)
#endif

__device__ __forceinline__ f16x8 cvt8(const float* p) {
    float4 a = *(const float4*)p;
    float4 b = *(const float4*)(p + 4);
    f16x8 r;
    r[0] = (f16)a.x; r[1] = (f16)a.y; r[2] = (f16)a.z; r[3] = (f16)a.w;
    r[4] = (f16)b.x; r[5] = (f16)b.y; r[6] = (f16)b.z; r[7] = (f16)b.w;
    return r;
}

// ---------------- kernel 1: qkv GEMM, in-LDS x transpose + l2norm ----------
// (unchanged from R8-passed build)
#define XROW 40   // 32 c + 8 pad

__global__ __launch_bounds__(256, 4) void qkv_mega(const float* __restrict__ x,
                                                   const float* __restrict__ wq,
                                                   f16* __restrict__ qh,
                                                   f16* __restrict__ kh,
                                                   f16* __restrict__ vh) {
    __shared__ __align__(16) f16 xl[32 * XROW];
    int t = threadIdx.x;
    int wave = t >> 6, lane = t & 63;
    int quad = lane >> 4, col = lane & 15;
    int b = blockIdx.z;
    int i0 = blockIdx.x * 32;
    int o0w = blockIdx.y * 128 + wave * 32;   // one 32-dh head per wave

    int sc = t >> 3;      // 0..31: local c row
    int iseg = t & 7;     // i group of 4
    const float* xb = x + (size_t)b * CC * NN + i0 + iseg * 4;

    f32x4 c[2][2];
#pragma unroll
    for (int mt = 0; mt < 2; mt++)
#pragma unroll
        for (int nt = 0; nt < 2; nt++) c[mt][nt] = f32x4{0.f, 0.f, 0.f, 0.f};

#pragma unroll
    for (int k0 = 0; k0 < CC; k0 += 32) {
        float4 xv = *(const float4*)(xb + (size_t)(k0 + sc) * NN);
        __syncthreads();   // prior iter's frag reads done before overwrite
        xl[(iseg * 4 + 0) * XROW + sc] = (f16)xv.x;
        xl[(iseg * 4 + 1) * XROW + sc] = (f16)xv.y;
        xl[(iseg * 4 + 2) * XROW + sc] = (f16)xv.z;
        xl[(iseg * 4 + 3) * XROW + sc] = (f16)xv.w;
        __syncthreads();
        f16x8 bf0 = *(const f16x8*)(xl + (size_t)col * XROW + quad * 8);
        f16x8 bf1 = *(const f16x8*)(xl + (size_t)(16 + col) * XROW + quad * 8);
#pragma unroll
        for (int mt = 0; mt < 2; mt++) {
            f16x8 a = cvt8(wq + (size_t)(o0w + mt * 16 + col) * CC + k0 + quad * 8);
            c[mt][0] = __builtin_amdgcn_mfma_f32_16x16x32_f16(a, bf0, c[mt][0], 0, 0, 0);
            c[mt][1] = __builtin_amdgcn_mfma_f32_16x16x32_f16(a, bf1, c[mt][1], 0, 0, 0);
        }
    }

    if (blockIdx.y < 2) {                 // Q (y=0) or K (y=1): l2norm
        int isQ = (blockIdx.y == 0);
        f16* dst = isQ ? qh : kh;
        int h = wave;                      // head index within b
        float pre = isQ ? QPRESCALE : 1.0f;
#pragma unroll
        for (int nt = 0; nt < 2; nt++) {
            float ss = 0.f;
#pragma unroll
            for (int m2 = 0; m2 < 2; m2++)
#pragma unroll
                for (int r = 0; r < 4; r++) {
                    float v = c[m2][nt][r];
                    ss = fmaf(v, v, ss);
                }
            ss += __shfl_xor(ss, 16);
            ss += __shfl_xor(ss, 32);
            float inv = pre / fmaxf(sqrtf(ss), 1e-12f);
            size_t row = ((size_t)(b * 4 + h) * NN + i0 + nt * 16 + col) * 32;
#pragma unroll
            for (int m2 = 0; m2 < 2; m2++) {
                f16x4 st;
#pragma unroll
                for (int r = 0; r < 4; r++) st[r] = (f16)(c[m2][nt][r] * inv);
                *(f16x4*)(dst + row + m2 * 16 + quad * 4) = st;
            }
        }
    } else {                               // V: [bh][d][i] layout
        int h = wave;
#pragma unroll
        for (int nt = 0; nt < 2; nt++) {
            int i = i0 + nt * 16 + col;
#pragma unroll
            for (int m2 = 0; m2 < 2; m2++)
#pragma unroll
                for (int r = 0; r < 4; r++)
                    vh[((size_t)(b * 4 + h) * 32 + m2 * 16 + quad * 4 + r) * NN + i] =
                        (f16)c[m2][nt][r];
        }
    }
}

// ---------------- kernel 2: LDS-staged MFMA flash attention, key-split ------
// Reverted VERBATIM to the R8/R11-passed 4-frag build (best measured: 46.7).
// q-scaling fully mapped: 32q=49.5 (R10), 64q=46.7 (R8), 128q=49.2 (R13) ->
// 64 q/wave is the local optimum of this structure.
#define KROW 40   // 32 d + 8 pad (f16) -> 80 B rows, b128-clean
#define VROW 72   // 64 keys + 8 pad   -> 144 B rows, b128-clean

__device__ __forceinline__ f16x8 expblk2(f32x4 sa, f32x4 sb) {
    u32x4 w;
    w[0] = __builtin_bit_cast(unsigned int,
            __builtin_amdgcn_cvt_pkrtz(EXP2F(sa[0]), EXP2F(sa[1])));
    w[1] = __builtin_bit_cast(unsigned int,
            __builtin_amdgcn_cvt_pkrtz(EXP2F(sa[2]), EXP2F(sa[3])));
    w[2] = __builtin_bit_cast(unsigned int,
            __builtin_amdgcn_cvt_pkrtz(EXP2F(sb[0]), EXP2F(sb[1])));
    w[3] = __builtin_bit_cast(unsigned int,
            __builtin_amdgcn_cvt_pkrtz(EXP2F(sb[2]), EXP2F(sb[3])));
    return __builtin_bit_cast(f16x8, w);
}

// one 32-key group (jb = 0 or 32) x 64 q (4 q-frags)
__device__ __forceinline__ void compute_g(const f16* kl, const f16* vl, int jb,
                                          int col, int quad, const f16x8 (&qB)[4],
                                          f32x4 (&o)[4][2], f32x4 (&lf)[4]) {
    f16x8 kA = *(const f16x8*)(kl + (jb + col) * KROW + quad * 8);
    f16x8 kB = *(const f16x8*)(kl + (jb + 16 + col) * KROW + quad * 8);
    f16x8 v0 = *(const f16x8*)(vl + col * VROW + jb + quad * 8);
    f16x8 v1 = *(const f16x8*)(vl + (16 + col) * VROW + jb + quad * 8);
    const f32x4 zs = {-NSHIFT, -NSHIFT, -NSHIFT, -NSHIFT};
    f16 one = (f16)1.0f;
    f16x8 ones = {one, one, one, one, one, one, one, one};
#pragma unroll
    for (int f = 0; f < 4; f++) {
        f32x4 sa = __builtin_amdgcn_mfma_f32_16x16x32_f16(kA, qB[f], zs, 0, 0, 0);
        f32x4 sb = __builtin_amdgcn_mfma_f32_16x16x32_f16(kB, qB[f], zs, 0, 0, 0);
        f16x8 p = expblk2(sa, sb);
        o[f][0] = __builtin_amdgcn_mfma_f32_16x16x32_f16(p, v0, o[f][0], 0, 0, 0);
        o[f][1] = __builtin_amdgcn_mfma_f32_16x16x32_f16(p, v1, o[f][1], 0, 0, 0);
        lf[f]   = __builtin_amdgcn_mfma_f32_16x16x32_f16(p, ones, lf[f], 0, 0, 0);
    }
}

template <int SPLIT>
__global__ __launch_bounds__(256, 4) void attn_mfma(const f16* __restrict__ qh,
                                                    const f16* __restrict__ kh,
                                                    const f16* __restrict__ vh,
                                                    float* __restrict__ op,
                                                    float* __restrict__ lp,
                                                    f16* __restrict__ att16) {
    __shared__ __align__(16) f16 klds[2][64 * KROW];
    __shared__ __align__(16) f16 vlds[2][32 * VROW];
    int t = threadIdx.x;
    int wave = t >> 6, lane = t & 63;
    int quad = lane >> 4, col = lane & 15;

    // grid = 256*SPLIT blocks; xcd grouping keeps K/V L2-resident (2 bh/XCD).
    int bid = blockIdx.x;
    int xcd = bid & 7;
    int slot = bid >> 3;                      // 0 .. 32*SPLIT-1
    int bh = xcd * 2 + slot / (16 * SPLIT);   // 0..15
    int rem = slot % (16 * SPLIT);
    int s = rem >> 4;                         // 0..SPLIT-1
    int i0 = (rem & 15) * 256;
    int iw = i0 + wave * 64;

    const int NT = 64 / SPLIT;                // 64-key tiles per block
    int kbase = s * (NN / SPLIT);

    const f16* qb = qh + (size_t)bh * NN * 32;
    const f16* kb = kh + (size_t)bh * NN * 32 + (size_t)kbase * 32;
    const f16* vb = vh + (size_t)bh * 32 * NN + kbase;

    f16x8 qB[4];
#pragma unroll
    for (int f = 0; f < 4; f++)
        qB[f] = *(const f16x8*)(qb + (size_t)(iw + f * 16 + col) * 32 + quad * 8);

    f32x4 o[4][2], lf[4];
#pragma unroll
    for (int f = 0; f < 4; f++) {
        o[f][0] = f32x4{0.f, 0.f, 0.f, 0.f};
        o[f][1] = f32x4{0.f, 0.f, 0.f, 0.f};
        lf[f]   = f32x4{0.f, 0.f, 0.f, 0.f};
    }

    // staging: K rows gathered in PV-permuted order (ksrc bijection) so P
    // frag concat is the native 16x16x32 A layout; V natural [dh][key].
    int ktr = t >> 2, kts = t & 3;
    int ksrc = (ktr & 32) | ((ktr & 12) << 1) | ((ktr & 16) >> 2) | (ktr & 3);
    int vtr = t >> 3, vts = t & 7;

    f16x8 kr, vr;
    kr = *(const f16x8*)(kb + (size_t)(0 + ksrc) * 32 + kts * 8);
    vr = *(const f16x8*)(vb + (size_t)vtr * NN + 0 + vts * 8);
    *(f16x8*)(&klds[0][0] + ktr * KROW + kts * 8) = kr;
    *(f16x8*)(&vlds[0][0] + vtr * VROW + vts * 8) = vr;
    __syncthreads();
    kr = *(const f16x8*)(kb + (size_t)(64 + ksrc) * 32 + kts * 8);
    vr = *(const f16x8*)(vb + (size_t)vtr * NN + 64 + vts * 8);

    for (int tile = 0; tile < NT - 2; tile++) {
        int buf = tile & 1;
        const f16* kl = &klds[buf][0];
        const f16* vl = &vlds[buf][0];
        compute_g(kl, vl, 0, col, quad, qB, o, lf);
        compute_g(kl, vl, 32, col, quad, qB, o, lf);
        *(f16x8*)(&klds[buf ^ 1][0] + ktr * KROW + kts * 8) = kr;
        *(f16x8*)(&vlds[buf ^ 1][0] + vtr * VROW + vts * 8) = vr;
        __syncthreads();
        int j0 = (tile + 2) * 64;
        kr = *(const f16x8*)(kb + (size_t)(j0 + ksrc) * 32 + kts * 8);
        vr = *(const f16x8*)(vb + (size_t)vtr * NN + j0 + vts * 8);
    }
    {   // tile NT-2 (buf 0); kr/vr hold tile NT-1
        compute_g(&klds[0][0], &vlds[0][0], 0, col, quad, qB, o, lf);
        compute_g(&klds[0][0], &vlds[0][0], 32, col, quad, qB, o, lf);
        *(f16x8*)(&klds[1][0] + ktr * KROW + kts * 8) = kr;
        *(f16x8*)(&vlds[1][0] + vtr * VROW + vts * 8) = vr;
        __syncthreads();
    }
    {   // tile NT-1 (buf 1)
        compute_g(&klds[1][0], &vlds[1][0], 0, col, quad, qB, o, lf);
        compute_g(&klds[1][0], &vlds[1][0], 32, col, quad, qB, o, lf);
    }

    // lf[f][r] = sum_k p for query row iw + f*16 + quad*4 + r (replicated
    // across col lanes).
    if constexpr (SPLIT == 1) {
        int b = bh >> 2, h = bh & 3;
        f16* ab = att16 + (size_t)b * NN * HID + h * 32;
#pragma unroll
        for (int f = 0; f < 4; f++)
#pragma unroll
            for (int r = 0; r < 4; r++) {
                float inv = __builtin_amdgcn_rcpf(lf[f][r]);
                size_t row = (size_t)(iw + f * 16 + quad * 4 + r) * HID;
                ab[row + col]      = (f16)(o[f][0][r] * inv);
                ab[row + 16 + col] = (f16)(o[f][1][r] * inv);
            }
    } else {
        // f32 partials: op[(s*16+bh)][q][dh], lp[(s*16+bh)][q]
        float* ob = op + (size_t)(s * 16 + bh) * NN * 32;
#pragma unroll
        for (int f = 0; f < 4; f++)
#pragma unroll
            for (int r = 0; r < 4; r++) {
                size_t rr = (size_t)(iw + f * 16 + quad * 4 + r) * 32;
                ob[rr + col]      = o[f][0][r];
                ob[rr + 16 + col] = o[f][1][r];
            }
        if (col == 0) {
            float* lb = lp + (size_t)(s * 16 + bh) * NN;
#pragma unroll
            for (int f = 0; f < 4; f++)
#pragma unroll
                for (int r = 0; r < 4; r++)
                    lb[iw + f * 16 + quad * 4 + r] = lf[f][r];
        }
    }
}

// ---------------- kernel 3 (fused): combine + output projection ------------
// R14 experiment: R11's out_fused ran at 512 blocks = 2 blocks/CU = 2
// waves/SIMD with 16 L3-latency op loads per k-step -> the same latency-
// bound signature attn had in R0. This version: o-tile 64 -> grid 1024 =
// 4 blocks/CU (LDS 17.4 KB, ~60 VGPR), op re-read 4x (128 MB, L3-resident).
// Arithmetic (s-order adds, rcpf, RNE casts) BIT-IDENTICAL to R11.
#define WROW 136   // 128 k + 8 pad (f16)

template <int NS>
__global__ __launch_bounds__(256, 4) void out_fused(const float* __restrict__ op,
                                                    const float* __restrict__ lp,
                                                    const float* __restrict__ wo,
                                                    const float* __restrict__ bo,
                                                    float* __restrict__ out) {
    __shared__ __align__(16) f16 wol[64 * WROW];   // 17.4 KB
    int t = threadIdx.x;
    int wave = t >> 6, lane = t & 63;
    int quad = lane >> 4, col = lane & 15;
    int b = blockIdx.z;
    int i0w = blockIdx.x * 64 + wave * 16;
    int o0 = blockIdx.y * 64;

    // stage wo[o0..o0+64)[0..128) -> f16 LDS (each thread: 1 row-quarter)
    {
        int row = t >> 2;            // 0..63
        int kq = (t & 3) * 32;       // 0,32,64,96
        const float* src = wo + (size_t)(o0 + row) * HID + kq;
        f16* d = wol + row * WROW + kq;
#pragma unroll
        for (int j = 0; j < 4; j++) {
            float4 a = *(const float4*)(src + j * 8);
            float4 bq = *(const float4*)(src + j * 8 + 4);
            f16x8 s;
            s[0] = (f16)a.x; s[1] = (f16)a.y; s[2] = (f16)a.z; s[3] = (f16)a.w;
            s[4] = (f16)bq.x; s[5] = (f16)bq.y; s[6] = (f16)bq.z; s[7] = (f16)bq.w;
            *(f16x8*)(d + j * 8) = s;
        }
    }
    __syncthreads();

    int i = i0w + col;               // this lane's A-row
    // per-lane inverse denominators for all 4 heads (matches combine: seq
    // adds over s, then rcpf)
    float invl[4];
#pragma unroll
    for (int h = 0; h < 4; h++) {
        float l = 0.f;
#pragma unroll
        for (int s = 0; s < NS; s++)
            l += lp[(size_t)(s * 16 + b * 4 + h) * NN + i];
        invl[h] = __builtin_amdgcn_rcpf(l);
    }

    const f32x4 z = {0.f, 0.f, 0.f, 0.f};
    f32x4 c[4];
#pragma unroll
    for (int ot = 0; ot < 4; ot++) c[ot] = z;

#pragma unroll
    for (int k0 = 0; k0 < HID; k0 += 32) {
        int h = k0 >> 5;
        f32x4 accA = z, accB = z;
#pragma unroll
        for (int s = 0; s < NS; s++) {
            const float* src = op + ((size_t)(s * 16 + b * 4 + h) * NN + i) * 32 + quad * 8;
            accA += *(const f32x4*)(src);
            accB += *(const f32x4*)(src + 4);
        }
        float iv = invl[h];
        f16x8 a0;
        a0[0] = (f16)(accA[0] * iv); a0[1] = (f16)(accA[1] * iv);
        a0[2] = (f16)(accA[2] * iv); a0[3] = (f16)(accA[3] * iv);
        a0[4] = (f16)(accB[0] * iv); a0[5] = (f16)(accB[1] * iv);
        a0[6] = (f16)(accB[2] * iv); a0[7] = (f16)(accB[3] * iv);
#pragma unroll
        for (int ot = 0; ot < 4; ot++) {
            f16x8 bf = *(const f16x8*)(wol + (size_t)(ot * 16 + col) * WROW + k0 + quad * 8);
            c[ot] = __builtin_amdgcn_mfma_f32_16x16x32_f16(a0, bf, c[ot], 0, 0, 0);
        }
    }

#pragma unroll
    for (int ot = 0; ot < 4; ot++) {
        int o = o0 + ot * 16 + col;
        float bias = bo[o];
        int ii = i0w + quad * 4;
        float4 st = {c[ot][0] + bias, c[ot][1] + bias,
                     c[ot][2] + bias, c[ot][3] + bias};
        *(float4*)(out + ((size_t)b * CC + o) * NN + ii) = st;
    }
}

// ---------------- kernel 3-fallback: output projection for SPLIT=1 ---------
__global__ __launch_bounds__(256, 4) void out_mfma(const f16* __restrict__ att16,
                                                   const float* __restrict__ wo,
                                                   const float* __restrict__ bo,
                                                   float* __restrict__ out) {
    __shared__ __align__(16) f16 wol[64 * WROW];
    int t = threadIdx.x;
    int wave = t >> 6, lane = t & 63;
    int quad = lane >> 4, col = lane & 15;
    int b = blockIdx.z;
    int i0w = blockIdx.x * 64 + wave * 16;
    int o0 = blockIdx.y * 64;
    const f16* ab = att16 + (size_t)b * NN * HID;

    {
        int row = t >> 2;            // 0..63
        int kq = (t & 3) * 32;       // 0,32,64,96
        const float* src = wo + (size_t)(o0 + row) * HID + kq;
        f16* d = wol + row * WROW + kq;
#pragma unroll
        for (int j = 0; j < 4; j++) {
            float4 a = *(const float4*)(src + j * 8);
            float4 bq = *(const float4*)(src + j * 8 + 4);
            f16x8 s;
            s[0] = (f16)a.x; s[1] = (f16)a.y; s[2] = (f16)a.z; s[3] = (f16)a.w;
            s[4] = (f16)bq.x; s[5] = (f16)bq.y; s[6] = (f16)bq.z; s[7] = (f16)bq.w;
            *(f16x8*)(d + j * 8) = s;
        }
    }
    __syncthreads();

    const f32x4 z = {0.f, 0.f, 0.f, 0.f};
    f32x4 c[4];
#pragma unroll
    for (int ot = 0; ot < 4; ot++) c[ot] = z;

#pragma unroll
    for (int k0 = 0; k0 < HID; k0 += 32) {
        f16x8 a0 = *(const f16x8*)(ab + (size_t)(i0w + col) * HID + k0 + quad * 8);
#pragma unroll
        for (int ot = 0; ot < 4; ot++) {
            f16x8 bf = *(const f16x8*)(wol + (size_t)(ot * 16 + col) * WROW + k0 + quad * 8);
            c[ot] = __builtin_amdgcn_mfma_f32_16x16x32_f16(a0, bf, c[ot], 0, 0, 0);
        }
    }

#pragma unroll
    for (int ot = 0; ot < 4; ot++) {
        int o = o0 + ot * 16 + col;
        float bias = bo[o];
        int i = i0w + quad * 4;
        float4 st = {c[ot][0] + bias, c[ot][1] + bias,
                     c[ot][2] + bias, c[ot][3] + bias};
        *(float4*)(out + ((size_t)b * CC + o) * NN + i) = st;
    }
}

extern "C" void kernel_launch(void* const* d_in, const int* in_sizes, int n_in,
                              void* d_out, int out_size, void* d_ws, size_t ws_size,
                              hipStream_t stream) {
    const float* x     = (const float*)d_in[0];
    const float* w_qkv = (const float*)d_in[1];
    const float* w_out = (const float*)d_in[2];
    const float* b_out = (const float*)d_in[3];
    float* out = (float*)d_out;

    char* ws = (char*)d_ws;
    f16* qh    = (f16*)(ws);                        // 4 MB
    f16* kh    = (f16*)(ws + (4u << 20));           // 4 MB
    f16* vh    = (f16*)(ws + (8u << 20));           // 4 MB
    f16* att16 = (f16*)(ws + (12u << 20));          // 4 MB (SPLIT=1 path only)

    qkv_mega<<<dim3(NN / 32, 3, BB), 256, 0, stream>>>(x, w_qkv, qh, kh, vh);

    if (ws_size >= (50ull << 20)) {
        // SPLIT=4: op 32 MB @16, lp 1 MB @48; attn grid 1024 (R8 config)
        float* op = (float*)(ws + (16ull << 20));
        float* lp = (float*)(ws + (48ull << 20));
        attn_mfma<4><<<dim3(1024), 256, 0, stream>>>(qh, kh, vh, op, lp, att16);
        out_fused<4><<<dim3(NN / 64, CC / 64, BB), 256, 0, stream>>>(op, lp, w_out, b_out, out);
    } else if (ws_size >= (33ull << 20)) {
        // SPLIT=2: op 16 MB @16, lp 0.5 MB @32
        float* op = (float*)(ws + (16ull << 20));
        float* lp = (float*)(ws + (32ull << 20));
        attn_mfma<2><<<dim3(512), 256, 0, stream>>>(qh, kh, vh, op, lp, att16);
        out_fused<2><<<dim3(NN / 64, CC / 64, BB), 256, 0, stream>>>(op, lp, w_out, b_out, out);
    } else {
        attn_mfma<1><<<dim3(256), 256, 0, stream>>>(qh, kh, vh, nullptr, nullptr, att16);
        out_mfma<<<dim3(NN / 64, CC / 64, BB), 256, 0, stream>>>(att16, w_out, b_out, out);
    }
}

// Round 15
// 152.159 us; speedup vs baseline: 1.0233x; 1.0233x over previous
//
#include <hip/hip_runtime.h>
#include <math.h>

#define BB 4
#define CC 256
#define NHEAD 4
#define DH 32
#define NN 4096
#define HID 128

typedef _Float16 f16;
typedef _Float16 f16x8 __attribute__((ext_vector_type(8)));
typedef _Float16 f16x4 __attribute__((ext_vector_type(4)));
typedef float f32x4 __attribute__((ext_vector_type(4)));
typedef unsigned int u32x4 __attribute__((ext_vector_type(4)));

#define QPRESCALE 14.42695041f
#define NSHIFT 14.42695041f

#if __has_builtin(__builtin_amdgcn_exp2f)
#define EXP2F(x) __builtin_amdgcn_exp2f(x)
#else
#define EXP2F(x) __expf((x)*0.6931471805599453f)
#endif

__device__ __forceinline__ f16x8 cvt8(const float* p) {
    float4 a = *(const float4*)p;
    float4 b = *(const float4*)(p + 4);
    f16x8 r;
    r[0] = (f16)a.x; r[1] = (f16)a.y; r[2] = (f16)a.z; r[3] = (f16)a.w;
    r[4] = (f16)b.x; r[5] = (f16)b.y; r[6] = (f16)b.z; r[7] = (f16)b.w;
    return r;
}

// ---------------- kernel 1: qkv GEMM, in-LDS x transpose + l2norm ----------
// (unchanged from R8-passed build)
#define XROW 40   // 32 c + 8 pad

__global__ __launch_bounds__(256, 4) void qkv_mega(const float* __restrict__ x,
                                                   const float* __restrict__ wq,
                                                   f16* __restrict__ qh,
                                                   f16* __restrict__ kh,
                                                   f16* __restrict__ vh) {
    __shared__ __align__(16) f16 xl[32 * XROW];
    int t = threadIdx.x;
    int wave = t >> 6, lane = t & 63;
    int quad = lane >> 4, col = lane & 15;
    int b = blockIdx.z;
    int i0 = blockIdx.x * 32;
    int o0w = blockIdx.y * 128 + wave * 32;   // one 32-dh head per wave

    int sc = t >> 3;      // 0..31: local c row
    int iseg = t & 7;     // i group of 4
    const float* xb = x + (size_t)b * CC * NN + i0 + iseg * 4;

    f32x4 c[2][2];
#pragma unroll
    for (int mt = 0; mt < 2; mt++)
#pragma unroll
        for (int nt = 0; nt < 2; nt++) c[mt][nt] = f32x4{0.f, 0.f, 0.f, 0.f};

#pragma unroll
    for (int k0 = 0; k0 < CC; k0 += 32) {
        float4 xv = *(const float4*)(xb + (size_t)(k0 + sc) * NN);
        __syncthreads();   // prior iter's frag reads done before overwrite
        xl[(iseg * 4 + 0) * XROW + sc] = (f16)xv.x;
        xl[(iseg * 4 + 1) * XROW + sc] = (f16)xv.y;
        xl[(iseg * 4 + 2) * XROW + sc] = (f16)xv.z;
        xl[(iseg * 4 + 3) * XROW + sc] = (f16)xv.w;
        __syncthreads();
        f16x8 bf0 = *(const f16x8*)(xl + (size_t)col * XROW + quad * 8);
        f16x8 bf1 = *(const f16x8*)(xl + (size_t)(16 + col) * XROW + quad * 8);
#pragma unroll
        for (int mt = 0; mt < 2; mt++) {
            f16x8 a = cvt8(wq + (size_t)(o0w + mt * 16 + col) * CC + k0 + quad * 8);
            c[mt][0] = __builtin_amdgcn_mfma_f32_16x16x32_f16(a, bf0, c[mt][0], 0, 0, 0);
            c[mt][1] = __builtin_amdgcn_mfma_f32_16x16x32_f16(a, bf1, c[mt][1], 0, 0, 0);
        }
    }

    if (blockIdx.y < 2) {                 // Q (y=0) or K (y=1): l2norm
        int isQ = (blockIdx.y == 0);
        f16* dst = isQ ? qh : kh;
        int h = wave;                      // head index within b
        float pre = isQ ? QPRESCALE : 1.0f;
#pragma unroll
        for (int nt = 0; nt < 2; nt++) {
            float ss = 0.f;
#pragma unroll
            for (int m2 = 0; m2 < 2; m2++)
#pragma unroll
                for (int r = 0; r < 4; r++) {
                    float v = c[m2][nt][r];
                    ss = fmaf(v, v, ss);
                }
            ss += __shfl_xor(ss, 16);
            ss += __shfl_xor(ss, 32);
            float inv = pre / fmaxf(sqrtf(ss), 1e-12f);
            size_t row = ((size_t)(b * 4 + h) * NN + i0 + nt * 16 + col) * 32;
#pragma unroll
            for (int m2 = 0; m2 < 2; m2++) {
                f16x4 st;
#pragma unroll
                for (int r = 0; r < 4; r++) st[r] = (f16)(c[m2][nt][r] * inv);
                *(f16x4*)(dst + row + m2 * 16 + quad * 4) = st;
            }
        }
    } else {                               // V: [bh][d][i] layout
        int h = wave;
#pragma unroll
        for (int nt = 0; nt < 2; nt++) {
            int i = i0 + nt * 16 + col;
#pragma unroll
            for (int m2 = 0; m2 < 2; m2++)
#pragma unroll
                for (int r = 0; r < 4; r++)
                    vh[((size_t)(b * 4 + h) * 32 + m2 * 16 + quad * 4 + r) * NN + i] =
                        (f16)c[m2][nt][r];
        }
    }
}

// ---------------- kernel 2: LDS-staged MFMA flash attention, key-split ------
// R15: same R8 structure (64 q/wave local optimum; staging load-bearing),
// but the per-group compute is software-pipelined at f-granularity:
// QK(f+1)'s MFMAs are issued BEFORE exp(f), so the VALU exp chain overlaps
// in-flight matrix work (R14 counters: VALU 48% + MFMA 36% ~ sum to wall ->
// pipes serialized; m114 proves they can overlap). s_setprio(1) wraps MFMA
// clusters (T5: +4-7% attn). Accumulation order per f unchanged ->
// bit-identical output.
#define KROW 40   // 32 d + 8 pad (f16) -> 80 B rows, b128-clean
#define VROW 72   // 64 keys + 8 pad   -> 144 B rows, b128-clean

__device__ __forceinline__ f16x8 expblk2(f32x4 sa, f32x4 sb) {
    u32x4 w;
    w[0] = __builtin_bit_cast(unsigned int,
            __builtin_amdgcn_cvt_pkrtz(EXP2F(sa[0]), EXP2F(sa[1])));
    w[1] = __builtin_bit_cast(unsigned int,
            __builtin_amdgcn_cvt_pkrtz(EXP2F(sa[2]), EXP2F(sa[3])));
    w[2] = __builtin_bit_cast(unsigned int,
            __builtin_amdgcn_cvt_pkrtz(EXP2F(sb[0]), EXP2F(sb[1])));
    w[3] = __builtin_bit_cast(unsigned int,
            __builtin_amdgcn_cvt_pkrtz(EXP2F(sb[2]), EXP2F(sb[3])));
    return __builtin_bit_cast(f16x8, w);
}

// one 32-key group (jb = 0 or 32) x 64 q (4 q-frags), f-pipelined
__device__ __forceinline__ void compute_g(const f16* kl, const f16* vl, int jb,
                                          int col, int quad, const f16x8 (&qB)[4],
                                          f32x4 (&o)[4][2], f32x4 (&lf)[4]) {
    f16x8 kA = *(const f16x8*)(kl + (jb + col) * KROW + quad * 8);
    f16x8 kB = *(const f16x8*)(kl + (jb + 16 + col) * KROW + quad * 8);
    f16x8 v0 = *(const f16x8*)(vl + col * VROW + jb + quad * 8);
    f16x8 v1 = *(const f16x8*)(vl + (16 + col) * VROW + jb + quad * 8);
    const f32x4 zs = {-NSHIFT, -NSHIFT, -NSHIFT, -NSHIFT};
    f16 one = (f16)1.0f;
    f16x8 ones = {one, one, one, one, one, one, one, one};

    __builtin_amdgcn_s_setprio(1);
    f32x4 sa = __builtin_amdgcn_mfma_f32_16x16x32_f16(kA, qB[0], zs, 0, 0, 0);
    f32x4 sb = __builtin_amdgcn_mfma_f32_16x16x32_f16(kB, qB[0], zs, 0, 0, 0);
#pragma unroll
    for (int f = 0; f < 4; f++) {
        f32x4 na, nb;
        if (f < 3) {   // issue next f's QK before this f's exp: exp overlaps
            na = __builtin_amdgcn_mfma_f32_16x16x32_f16(kA, qB[f + 1], zs, 0, 0, 0);
            nb = __builtin_amdgcn_mfma_f32_16x16x32_f16(kB, qB[f + 1], zs, 0, 0, 0);
        }
        __builtin_amdgcn_s_setprio(0);
        f16x8 p = expblk2(sa, sb);
        __builtin_amdgcn_s_setprio(1);
        o[f][0] = __builtin_amdgcn_mfma_f32_16x16x32_f16(p, v0, o[f][0], 0, 0, 0);
        o[f][1] = __builtin_amdgcn_mfma_f32_16x16x32_f16(p, v1, o[f][1], 0, 0, 0);
        lf[f]   = __builtin_amdgcn_mfma_f32_16x16x32_f16(p, ones, lf[f], 0, 0, 0);
        if (f < 3) { sa = na; sb = nb; }
    }
    __builtin_amdgcn_s_setprio(0);
}

template <int SPLIT>
__global__ __launch_bounds__(256, 4) void attn_mfma(const f16* __restrict__ qh,
                                                    const f16* __restrict__ kh,
                                                    const f16* __restrict__ vh,
                                                    float* __restrict__ op,
                                                    float* __restrict__ lp,
                                                    f16* __restrict__ att16) {
    __shared__ __align__(16) f16 klds[2][64 * KROW];
    __shared__ __align__(16) f16 vlds[2][32 * VROW];
    int t = threadIdx.x;
    int wave = t >> 6, lane = t & 63;
    int quad = lane >> 4, col = lane & 15;

    // grid = 256*SPLIT blocks; xcd grouping keeps K/V L2-resident (2 bh/XCD).
    int bid = blockIdx.x;
    int xcd = bid & 7;
    int slot = bid >> 3;                      // 0 .. 32*SPLIT-1
    int bh = xcd * 2 + slot / (16 * SPLIT);   // 0..15
    int rem = slot % (16 * SPLIT);
    int s = rem >> 4;                         // 0..SPLIT-1
    int i0 = (rem & 15) * 256;
    int iw = i0 + wave * 64;

    const int NT = 64 / SPLIT;                // 64-key tiles per block
    int kbase = s * (NN / SPLIT);

    const f16* qb = qh + (size_t)bh * NN * 32;
    const f16* kb = kh + (size_t)bh * NN * 32 + (size_t)kbase * 32;
    const f16* vb = vh + (size_t)bh * 32 * NN + kbase;

    f16x8 qB[4];
#pragma unroll
    for (int f = 0; f < 4; f++)
        qB[f] = *(const f16x8*)(qb + (size_t)(iw + f * 16 + col) * 32 + quad * 8);

    f32x4 o[4][2], lf[4];
#pragma unroll
    for (int f = 0; f < 4; f++) {
        o[f][0] = f32x4{0.f, 0.f, 0.f, 0.f};
        o[f][1] = f32x4{0.f, 0.f, 0.f, 0.f};
        lf[f]   = f32x4{0.f, 0.f, 0.f, 0.f};
    }

    // staging: K rows gathered in PV-permuted order (ksrc bijection) so P
    // frag concat is the native 16x16x32 A layout; V natural [dh][key].
    int ktr = t >> 2, kts = t & 3;
    int ksrc = (ktr & 32) | ((ktr & 12) << 1) | ((ktr & 16) >> 2) | (ktr & 3);
    int vtr = t >> 3, vts = t & 7;

    f16x8 kr, vr;
    kr = *(const f16x8*)(kb + (size_t)(0 + ksrc) * 32 + kts * 8);
    vr = *(const f16x8*)(vb + (size_t)vtr * NN + 0 + vts * 8);
    *(f16x8*)(&klds[0][0] + ktr * KROW + kts * 8) = kr;
    *(f16x8*)(&vlds[0][0] + vtr * VROW + vts * 8) = vr;
    __syncthreads();
    kr = *(const f16x8*)(kb + (size_t)(64 + ksrc) * 32 + kts * 8);
    vr = *(const f16x8*)(vb + (size_t)vtr * NN + 64 + vts * 8);

    for (int tile = 0; tile < NT - 2; tile++) {
        int buf = tile & 1;
        const f16* kl = &klds[buf][0];
        const f16* vl = &vlds[buf][0];
        compute_g(kl, vl, 0, col, quad, qB, o, lf);
        compute_g(kl, vl, 32, col, quad, qB, o, lf);
        *(f16x8*)(&klds[buf ^ 1][0] + ktr * KROW + kts * 8) = kr;
        *(f16x8*)(&vlds[buf ^ 1][0] + vtr * VROW + vts * 8) = vr;
        __syncthreads();
        int j0 = (tile + 2) * 64;
        kr = *(const f16x8*)(kb + (size_t)(j0 + ksrc) * 32 + kts * 8);
        vr = *(const f16x8*)(vb + (size_t)vtr * NN + j0 + vts * 8);
    }
    {   // tile NT-2 (buf 0); kr/vr hold tile NT-1
        compute_g(&klds[0][0], &vlds[0][0], 0, col, quad, qB, o, lf);
        compute_g(&klds[0][0], &vlds[0][0], 32, col, quad, qB, o, lf);
        *(f16x8*)(&klds[1][0] + ktr * KROW + kts * 8) = kr;
        *(f16x8*)(&vlds[1][0] + vtr * VROW + vts * 8) = vr;
        __syncthreads();
    }
    {   // tile NT-1 (buf 1)
        compute_g(&klds[1][0], &vlds[1][0], 0, col, quad, qB, o, lf);
        compute_g(&klds[1][0], &vlds[1][0], 32, col, quad, qB, o, lf);
    }

    // lf[f][r] = sum_k p for query row iw + f*16 + quad*4 + r (replicated
    // across col lanes).
    if constexpr (SPLIT == 1) {
        int b = bh >> 2, h = bh & 3;
        f16* ab = att16 + (size_t)b * NN * HID + h * 32;
#pragma unroll
        for (int f = 0; f < 4; f++)
#pragma unroll
            for (int r = 0; r < 4; r++) {
                float inv = __builtin_amdgcn_rcpf(lf[f][r]);
                size_t row = (size_t)(iw + f * 16 + quad * 4 + r) * HID;
                ab[row + col]      = (f16)(o[f][0][r] * inv);
                ab[row + 16 + col] = (f16)(o[f][1][r] * inv);
            }
    } else {
        // f32 partials: op[(s*16+bh)][q][dh], lp[(s*16+bh)][q]
        float* ob = op + (size_t)(s * 16 + bh) * NN * 32;
#pragma unroll
        for (int f = 0; f < 4; f++)
#pragma unroll
            for (int r = 0; r < 4; r++) {
                size_t rr = (size_t)(iw + f * 16 + quad * 4 + r) * 32;
                ob[rr + col]      = o[f][0][r];
                ob[rr + 16 + col] = o[f][1][r];
            }
        if (col == 0) {
            float* lb = lp + (size_t)(s * 16 + bh) * NN;
#pragma unroll
            for (int f = 0; f < 4; f++)
#pragma unroll
                for (int r = 0; r < 4; r++)
                    lb[iw + f * 16 + quad * 4 + r] = lf[f][r];
        }
    }
}

// ---------------- kernel 3 (fused): combine + output projection ------------
// Reverted to the R11-passed 128-o version (R14's 64-o tile regressed: 4x op
// re-read cost more than the added occupancy bought).
#define WROW 136   // 128 k + 8 pad (f16)

template <int NS>
__global__ __launch_bounds__(256) void out_fused(const float* __restrict__ op,
                                                 const float* __restrict__ lp,
                                                 const float* __restrict__ wo,
                                                 const float* __restrict__ bo,
                                                 float* __restrict__ out) {
    __shared__ __align__(16) f16 wol[128 * WROW];   // 34.8 KB
    int t = threadIdx.x;
    int wave = t >> 6, lane = t & 63;
    int quad = lane >> 4, col = lane & 15;
    int b = blockIdx.z;
    int i0w = blockIdx.x * 64 + wave * 16;
    int o0 = blockIdx.y * 128;

    // stage wo[o0..o0+128)[0..128) -> f16 LDS (each thread: 1 row-half)
    {
        int row = t >> 1;            // 0..127
        int kh = (t & 1) * 64;       // 0 or 64
        const float* src = wo + (size_t)(o0 + row) * HID + kh;
        f16* d = wol + row * WROW + kh;
#pragma unroll
        for (int j = 0; j < 8; j++) {
            float4 a = *(const float4*)(src + j * 8);
            float4 bq = *(const float4*)(src + j * 8 + 4);
            f16x8 s;
            s[0] = (f16)a.x; s[1] = (f16)a.y; s[2] = (f16)a.z; s[3] = (f16)a.w;
            s[4] = (f16)bq.x; s[5] = (f16)bq.y; s[6] = (f16)bq.z; s[7] = (f16)bq.w;
            *(f16x8*)(d + j * 8) = s;
        }
    }
    __syncthreads();

    int i = i0w + col;               // this lane's A-row
    float invl[4];
#pragma unroll
    for (int h = 0; h < 4; h++) {
        float l = 0.f;
#pragma unroll
        for (int s = 0; s < NS; s++)
            l += lp[(size_t)(s * 16 + b * 4 + h) * NN + i];
        invl[h] = __builtin_amdgcn_rcpf(l);
    }

    const f32x4 z = {0.f, 0.f, 0.f, 0.f};
    f32x4 c[8];
#pragma unroll
    for (int ot = 0; ot < 8; ot++) c[ot] = z;

#pragma unroll
    for (int k0 = 0; k0 < HID; k0 += 32) {
        int h = k0 >> 5;
        f32x4 accA = z, accB = z;
#pragma unroll
        for (int s = 0; s < NS; s++) {
            const float* src = op + ((size_t)(s * 16 + b * 4 + h) * NN + i) * 32 + quad * 8;
            accA += *(const f32x4*)(src);
            accB += *(const f32x4*)(src + 4);
        }
        float iv = invl[h];
        f16x8 a0;
        a0[0] = (f16)(accA[0] * iv); a0[1] = (f16)(accA[1] * iv);
        a0[2] = (f16)(accA[2] * iv); a0[3] = (f16)(accA[3] * iv);
        a0[4] = (f16)(accB[0] * iv); a0[5] = (f16)(accB[1] * iv);
        a0[6] = (f16)(accB[2] * iv); a0[7] = (f16)(accB[3] * iv);
#pragma unroll
        for (int ot = 0; ot < 8; ot++) {
            f16x8 bf = *(const f16x8*)(wol + (size_t)(ot * 16 + col) * WROW + k0 + quad * 8);
            c[ot] = __builtin_amdgcn_mfma_f32_16x16x32_f16(a0, bf, c[ot], 0, 0, 0);
        }
    }

#pragma unroll
    for (int ot = 0; ot < 8; ot++) {
        int o = o0 + ot * 16 + col;
        float bias = bo[o];
        int ii = i0w + quad * 4;
        float4 st = {c[ot][0] + bias, c[ot][1] + bias,
                     c[ot][2] + bias, c[ot][3] + bias};
        *(float4*)(out + ((size_t)b * CC + o) * NN + ii) = st;
    }
}

// ---------------- kernel 3-fallback: output projection for SPLIT=1 ---------
__global__ __launch_bounds__(256, 4) void out_mfma(const f16* __restrict__ att16,
                                                   const float* __restrict__ wo,
                                                   const float* __restrict__ bo,
                                                   float* __restrict__ out) {
    __shared__ __align__(16) f16 wol[64 * WROW];
    int t = threadIdx.x;
    int wave = t >> 6, lane = t & 63;
    int quad = lane >> 4, col = lane & 15;
    int b = blockIdx.z;
    int i0w = blockIdx.x * 64 + wave * 16;
    int o0 = blockIdx.y * 64;
    const f16* ab = att16 + (size_t)b * NN * HID;

    {
        int row = t >> 2;            // 0..63
        int kq = (t & 3) * 32;       // 0,32,64,96
        const float* src = wo + (size_t)(o0 + row) * HID + kq;
        f16* d = wol + row * WROW + kq;
#pragma unroll
        for (int j = 0; j < 4; j++) {
            float4 a = *(const float4*)(src + j * 8);
            float4 bq = *(const float4*)(src + j * 8 + 4);
            f16x8 s;
            s[0] = (f16)a.x; s[1] = (f16)a.y; s[2] = (f16)a.z; s[3] = (f16)a.w;
            s[4] = (f16)bq.x; s[5] = (f16)bq.y; s[6] = (f16)bq.z; s[7] = (f16)bq.w;
            *(f16x8*)(d + j * 8) = s;
        }
    }
    __syncthreads();

    const f32x4 z = {0.f, 0.f, 0.f, 0.f};
    f32x4 c[4];
#pragma unroll
    for (int ot = 0; ot < 4; ot++) c[ot] = z;

#pragma unroll
    for (int k0 = 0; k0 < HID; k0 += 32) {
        f16x8 a0 = *(const f16x8*)(ab + (size_t)(i0w + col) * HID + k0 + quad * 8);
#pragma unroll
        for (int ot = 0; ot < 4; ot++) {
            f16x8 bf = *(const f16x8*)(wol + (size_t)(ot * 16 + col) * WROW + k0 + quad * 8);
            c[ot] = __builtin_amdgcn_mfma_f32_16x16x32_f16(a0, bf, c[ot], 0, 0, 0);
        }
    }

#pragma unroll
    for (int ot = 0; ot < 4; ot++) {
        int o = o0 + ot * 16 + col;
        float bias = bo[o];
        int i = i0w + quad * 4;
        float4 st = {c[ot][0] + bias, c[ot][1] + bias,
                     c[ot][2] + bias, c[ot][3] + bias};
        *(float4*)(out + ((size_t)b * CC + o) * NN + i) = st;
    }
}

extern "C" void kernel_launch(void* const* d_in, const int* in_sizes, int n_in,
                              void* d_out, int out_size, void* d_ws, size_t ws_size,
                              hipStream_t stream) {
    const float* x     = (const float*)d_in[0];
    const float* w_qkv = (const float*)d_in[1];
    const float* w_out = (const float*)d_in[2];
    const float* b_out = (const float*)d_in[3];
    float* out = (float*)d_out;

    char* ws = (char*)d_ws;
    f16* qh    = (f16*)(ws);                        // 4 MB
    f16* kh    = (f16*)(ws + (4u << 20));           // 4 MB
    f16* vh    = (f16*)(ws + (8u << 20));           // 4 MB
    f16* att16 = (f16*)(ws + (12u << 20));          // 4 MB (SPLIT=1 path only)

    qkv_mega<<<dim3(NN / 32, 3, BB), 256, 0, stream>>>(x, w_qkv, qh, kh, vh);

    if (ws_size >= (50ull << 20)) {
        // SPLIT=4: op 32 MB @16, lp 1 MB @48; attn grid 1024 (R8 config)
        float* op = (float*)(ws + (16ull << 20));
        float* lp = (float*)(ws + (48ull << 20));
        attn_mfma<4><<<dim3(1024), 256, 0, stream>>>(qh, kh, vh, op, lp, att16);
        out_fused<4><<<dim3(NN / 64, 2, BB), 256, 0, stream>>>(op, lp, w_out, b_out, out);
    } else if (ws_size >= (33ull << 20)) {
        // SPLIT=2: op 16 MB @16, lp 0.5 MB @32
        float* op = (float*)(ws + (16ull << 20));
        float* lp = (float*)(ws + (32ull << 20));
        attn_mfma<2><<<dim3(512), 256, 0, stream>>>(qh, kh, vh, op, lp, att16);
        out_fused<2><<<dim3(NN / 64, 2, BB), 256, 0, stream>>>(op, lp, w_out, b_out, out);
    } else {
        attn_mfma<1><<<dim3(256), 256, 0, stream>>>(qh, kh, vh, nullptr, nullptr, att16);
        out_mfma<<<dim3(NN / 64, CC / 64, BB), 256, 0, stream>>>(att16, w_out, b_out, out);
    }
}

// Round 16
// 149.617 us; speedup vs baseline: 1.0406x; 1.0170x over previous
//
#include <hip/hip_runtime.h>
#include <math.h>

#define BB 4
#define CC 256
#define NHEAD 4
#define DH 32
#define NN 4096
#define HID 128

typedef _Float16 f16;
typedef _Float16 f16x8 __attribute__((ext_vector_type(8)));
typedef _Float16 f16x4 __attribute__((ext_vector_type(4)));
typedef float f32x4 __attribute__((ext_vector_type(4)));
typedef unsigned int u32x4 __attribute__((ext_vector_type(4)));

#define QPRESCALE 14.42695041f
#define NSHIFT 14.42695041f

#if __has_builtin(__builtin_amdgcn_exp2f)
#define EXP2F(x) __builtin_amdgcn_exp2f(x)
#else
#define EXP2F(x) __expf((x)*0.6931471805599453f)
#endif

__device__ __forceinline__ f16x8 cvt8(const float* p) {
    float4 a = *(const float4*)p;
    float4 b = *(const float4*)(p + 4);
    f16x8 r;
    r[0] = (f16)a.x; r[1] = (f16)a.y; r[2] = (f16)a.z; r[3] = (f16)a.w;
    r[4] = (f16)b.x; r[5] = (f16)b.y; r[6] = (f16)b.z; r[7] = (f16)b.w;
    return r;
}

// ---------------- kernel 1: qkv GEMM, in-LDS x transpose + l2norm ----------
// (unchanged from R8-passed build)
#define XROW 40   // 32 c + 8 pad

__global__ __launch_bounds__(256, 4) void qkv_mega(const float* __restrict__ x,
                                                   const float* __restrict__ wq,
                                                   f16* __restrict__ qh,
                                                   f16* __restrict__ kh,
                                                   f16* __restrict__ vh) {
    __shared__ __align__(16) f16 xl[32 * XROW];
    int t = threadIdx.x;
    int wave = t >> 6, lane = t & 63;
    int quad = lane >> 4, col = lane & 15;
    int b = blockIdx.z;
    int i0 = blockIdx.x * 32;
    int o0w = blockIdx.y * 128 + wave * 32;   // one 32-dh head per wave

    int sc = t >> 3;      // 0..31: local c row
    int iseg = t & 7;     // i group of 4
    const float* xb = x + (size_t)b * CC * NN + i0 + iseg * 4;

    f32x4 c[2][2];
#pragma unroll
    for (int mt = 0; mt < 2; mt++)
#pragma unroll
        for (int nt = 0; nt < 2; nt++) c[mt][nt] = f32x4{0.f, 0.f, 0.f, 0.f};

#pragma unroll
    for (int k0 = 0; k0 < CC; k0 += 32) {
        float4 xv = *(const float4*)(xb + (size_t)(k0 + sc) * NN);
        __syncthreads();   // prior iter's frag reads done before overwrite
        xl[(iseg * 4 + 0) * XROW + sc] = (f16)xv.x;
        xl[(iseg * 4 + 1) * XROW + sc] = (f16)xv.y;
        xl[(iseg * 4 + 2) * XROW + sc] = (f16)xv.z;
        xl[(iseg * 4 + 3) * XROW + sc] = (f16)xv.w;
        __syncthreads();
        f16x8 bf0 = *(const f16x8*)(xl + (size_t)col * XROW + quad * 8);
        f16x8 bf1 = *(const f16x8*)(xl + (size_t)(16 + col) * XROW + quad * 8);
#pragma unroll
        for (int mt = 0; mt < 2; mt++) {
            f16x8 a = cvt8(wq + (size_t)(o0w + mt * 16 + col) * CC + k0 + quad * 8);
            c[mt][0] = __builtin_amdgcn_mfma_f32_16x16x32_f16(a, bf0, c[mt][0], 0, 0, 0);
            c[mt][1] = __builtin_amdgcn_mfma_f32_16x16x32_f16(a, bf1, c[mt][1], 0, 0, 0);
        }
    }

    if (blockIdx.y < 2) {                 // Q (y=0) or K (y=1): l2norm
        int isQ = (blockIdx.y == 0);
        f16* dst = isQ ? qh : kh;
        int h = wave;                      // head index within b
        float pre = isQ ? QPRESCALE : 1.0f;
#pragma unroll
        for (int nt = 0; nt < 2; nt++) {
            float ss = 0.f;
#pragma unroll
            for (int m2 = 0; m2 < 2; m2++)
#pragma unroll
                for (int r = 0; r < 4; r++) {
                    float v = c[m2][nt][r];
                    ss = fmaf(v, v, ss);
                }
            ss += __shfl_xor(ss, 16);
            ss += __shfl_xor(ss, 32);
            float inv = pre / fmaxf(sqrtf(ss), 1e-12f);
            size_t row = ((size_t)(b * 4 + h) * NN + i0 + nt * 16 + col) * 32;
#pragma unroll
            for (int m2 = 0; m2 < 2; m2++) {
                f16x4 st;
#pragma unroll
                for (int r = 0; r < 4; r++) st[r] = (f16)(c[m2][nt][r] * inv);
                *(f16x4*)(dst + row + m2 * 16 + quad * 4) = st;
            }
        }
    } else {                               // V: [bh][d][i] layout
        int h = wave;
#pragma unroll
        for (int nt = 0; nt < 2; nt++) {
            int i = i0 + nt * 16 + col;
#pragma unroll
            for (int m2 = 0; m2 < 2; m2++)
#pragma unroll
                for (int r = 0; r < 4; r++)
                    vh[((size_t)(b * 4 + h) * 32 + m2 * 16 + quad * 4 + r) * NN + i] =
                        (f16)c[m2][nt][r];
        }
    }
}

// ---------------- kernel 2: LDS-staged MFMA flash attention, key-split ------
// Reverted VERBATIM to the R8/R11-passed 4-frag build (best measured: 46.7).
// Schedule-space exhausted: TLP (R10), L2-direct (R12), f-pipeline+setprio
// (R15) all null or worse; 64 q/wave + SPLIT=4 + LDS double-buffer is the
// measured optimum of this structure.
#define KROW 40   // 32 d + 8 pad (f16) -> 80 B rows, b128-clean
#define VROW 72   // 64 keys + 8 pad   -> 144 B rows, b128-clean

__device__ __forceinline__ f16x8 expblk2(f32x4 sa, f32x4 sb) {
    u32x4 w;
    w[0] = __builtin_bit_cast(unsigned int,
            __builtin_amdgcn_cvt_pkrtz(EXP2F(sa[0]), EXP2F(sa[1])));
    w[1] = __builtin_bit_cast(unsigned int,
            __builtin_amdgcn_cvt_pkrtz(EXP2F(sa[2]), EXP2F(sa[3])));
    w[2] = __builtin_bit_cast(unsigned int,
            __builtin_amdgcn_cvt_pkrtz(EXP2F(sb[0]), EXP2F(sb[1])));
    w[3] = __builtin_bit_cast(unsigned int,
            __builtin_amdgcn_cvt_pkrtz(EXP2F(sb[2]), EXP2F(sb[3])));
    return __builtin_bit_cast(f16x8, w);
}

// one 32-key group (jb = 0 or 32) x 64 q (4 q-frags)
__device__ __forceinline__ void compute_g(const f16* kl, const f16* vl, int jb,
                                          int col, int quad, const f16x8 (&qB)[4],
                                          f32x4 (&o)[4][2], f32x4 (&lf)[4]) {
    f16x8 kA = *(const f16x8*)(kl + (jb + col) * KROW + quad * 8);
    f16x8 kB = *(const f16x8*)(kl + (jb + 16 + col) * KROW + quad * 8);
    f16x8 v0 = *(const f16x8*)(vl + col * VROW + jb + quad * 8);
    f16x8 v1 = *(const f16x8*)(vl + (16 + col) * VROW + jb + quad * 8);
    const f32x4 zs = {-NSHIFT, -NSHIFT, -NSHIFT, -NSHIFT};
    f16 one = (f16)1.0f;
    f16x8 ones = {one, one, one, one, one, one, one, one};
#pragma unroll
    for (int f = 0; f < 4; f++) {
        f32x4 sa = __builtin_amdgcn_mfma_f32_16x16x32_f16(kA, qB[f], zs, 0, 0, 0);
        f32x4 sb = __builtin_amdgcn_mfma_f32_16x16x32_f16(kB, qB[f], zs, 0, 0, 0);
        f16x8 p = expblk2(sa, sb);
        o[f][0] = __builtin_amdgcn_mfma_f32_16x16x32_f16(p, v0, o[f][0], 0, 0, 0);
        o[f][1] = __builtin_amdgcn_mfma_f32_16x16x32_f16(p, v1, o[f][1], 0, 0, 0);
        lf[f]   = __builtin_amdgcn_mfma_f32_16x16x32_f16(p, ones, lf[f], 0, 0, 0);
    }
}

template <int SPLIT>
__global__ __launch_bounds__(256, 4) void attn_mfma(const f16* __restrict__ qh,
                                                    const f16* __restrict__ kh,
                                                    const f16* __restrict__ vh,
                                                    float* __restrict__ op,
                                                    float* __restrict__ lp,
                                                    f16* __restrict__ att16) {
    __shared__ __align__(16) f16 klds[2][64 * KROW];
    __shared__ __align__(16) f16 vlds[2][32 * VROW];
    int t = threadIdx.x;
    int wave = t >> 6, lane = t & 63;
    int quad = lane >> 4, col = lane & 15;

    // grid = 256*SPLIT blocks; xcd grouping keeps K/V L2-resident (2 bh/XCD).
    int bid = blockIdx.x;
    int xcd = bid & 7;
    int slot = bid >> 3;                      // 0 .. 32*SPLIT-1
    int bh = xcd * 2 + slot / (16 * SPLIT);   // 0..15
    int rem = slot % (16 * SPLIT);
    int s = rem >> 4;                         // 0..SPLIT-1
    int i0 = (rem & 15) * 256;
    int iw = i0 + wave * 64;

    const int NT = 64 / SPLIT;                // 64-key tiles per block
    int kbase = s * (NN / SPLIT);

    const f16* qb = qh + (size_t)bh * NN * 32;
    const f16* kb = kh + (size_t)bh * NN * 32 + (size_t)kbase * 32;
    const f16* vb = vh + (size_t)bh * 32 * NN + kbase;

    f16x8 qB[4];
#pragma unroll
    for (int f = 0; f < 4; f++)
        qB[f] = *(const f16x8*)(qb + (size_t)(iw + f * 16 + col) * 32 + quad * 8);

    f32x4 o[4][2], lf[4];
#pragma unroll
    for (int f = 0; f < 4; f++) {
        o[f][0] = f32x4{0.f, 0.f, 0.f, 0.f};
        o[f][1] = f32x4{0.f, 0.f, 0.f, 0.f};
        lf[f]   = f32x4{0.f, 0.f, 0.f, 0.f};
    }

    // staging: K rows gathered in PV-permuted order (ksrc bijection) so P
    // frag concat is the native 16x16x32 A layout; V natural [dh][key].
    int ktr = t >> 2, kts = t & 3;
    int ksrc = (ktr & 32) | ((ktr & 12) << 1) | ((ktr & 16) >> 2) | (ktr & 3);
    int vtr = t >> 3, vts = t & 7;

    f16x8 kr, vr;
    kr = *(const f16x8*)(kb + (size_t)(0 + ksrc) * 32 + kts * 8);
    vr = *(const f16x8*)(vb + (size_t)vtr * NN + 0 + vts * 8);
    *(f16x8*)(&klds[0][0] + ktr * KROW + kts * 8) = kr;
    *(f16x8*)(&vlds[0][0] + vtr * VROW + vts * 8) = vr;
    __syncthreads();
    kr = *(const f16x8*)(kb + (size_t)(64 + ksrc) * 32 + kts * 8);
    vr = *(const f16x8*)(vb + (size_t)vtr * NN + 64 + vts * 8);

    for (int tile = 0; tile < NT - 2; tile++) {
        int buf = tile & 1;
        const f16* kl = &klds[buf][0];
        const f16* vl = &vlds[buf][0];
        compute_g(kl, vl, 0, col, quad, qB, o, lf);
        compute_g(kl, vl, 32, col, quad, qB, o, lf);
        *(f16x8*)(&klds[buf ^ 1][0] + ktr * KROW + kts * 8) = kr;
        *(f16x8*)(&vlds[buf ^ 1][0] + vtr * VROW + vts * 8) = vr;
        __syncthreads();
        int j0 = (tile + 2) * 64;
        kr = *(const f16x8*)(kb + (size_t)(j0 + ksrc) * 32 + kts * 8);
        vr = *(const f16x8*)(vb + (size_t)vtr * NN + j0 + vts * 8);
    }
    {   // tile NT-2 (buf 0); kr/vr hold tile NT-1
        compute_g(&klds[0][0], &vlds[0][0], 0, col, quad, qB, o, lf);
        compute_g(&klds[0][0], &vlds[0][0], 32, col, quad, qB, o, lf);
        *(f16x8*)(&klds[1][0] + ktr * KROW + kts * 8) = kr;
        *(f16x8*)(&vlds[1][0] + vtr * VROW + vts * 8) = vr;
        __syncthreads();
    }
    {   // tile NT-1 (buf 1)
        compute_g(&klds[1][0], &vlds[1][0], 0, col, quad, qB, o, lf);
        compute_g(&klds[1][0], &vlds[1][0], 32, col, quad, qB, o, lf);
    }

    // lf[f][r] = sum_k p for query row iw + f*16 + quad*4 + r (replicated
    // across col lanes).
    if constexpr (SPLIT == 1) {
        int b = bh >> 2, h = bh & 3;
        f16* ab = att16 + (size_t)b * NN * HID + h * 32;
#pragma unroll
        for (int f = 0; f < 4; f++)
#pragma unroll
            for (int r = 0; r < 4; r++) {
                float inv = __builtin_amdgcn_rcpf(lf[f][r]);
                size_t row = (size_t)(iw + f * 16 + quad * 4 + r) * HID;
                ab[row + col]      = (f16)(o[f][0][r] * inv);
                ab[row + 16 + col] = (f16)(o[f][1][r] * inv);
            }
    } else {
        // f32 partials: op[(s*16+bh)][q][dh], lp[(s*16+bh)][q]
        float* ob = op + (size_t)(s * 16 + bh) * NN * 32;
#pragma unroll
        for (int f = 0; f < 4; f++)
#pragma unroll
            for (int r = 0; r < 4; r++) {
                size_t rr = (size_t)(iw + f * 16 + quad * 4 + r) * 32;
                ob[rr + col]      = o[f][0][r];
                ob[rr + 16 + col] = o[f][1][r];
            }
        if (col == 0) {
            float* lb = lp + (size_t)(s * 16 + bh) * NN;
#pragma unroll
            for (int f = 0; f < 4; f++)
#pragma unroll
                for (int r = 0; r < 4; r++)
                    lb[iw + f * 16 + quad * 4 + r] = lf[f][r];
        }
    }
}

// ---------------- kernel 3 (fused): combine + output projection ------------
// R16: o-tile 256 (ALL outputs in one block) -> op read ONCE (was 2x in
// R11, 4x in R14). Traffic 80 -> 48 MB; R14 measured this kernel as
// traffic-bound (+64 MB cost +3.7 us), so predict -2..-4 us. wo staged once
// at 68 KB LDS; c[16] acc ~64 VGPR; grid 256 = 1 block/CU. Arithmetic
// (s-order adds, rcpf, RNE casts) BIT-IDENTICAL to R11.
#define WROW 136   // 128 k + 8 pad (f16)

template <int NS>
__global__ __launch_bounds__(256) void out_fused(const float* __restrict__ op,
                                                 const float* __restrict__ lp,
                                                 const float* __restrict__ wo,
                                                 const float* __restrict__ bo,
                                                 float* __restrict__ out) {
    __shared__ __align__(16) f16 wol[256 * WROW];   // 68 KB
    int t = threadIdx.x;
    int wave = t >> 6, lane = t & 63;
    int quad = lane >> 4, col = lane & 15;
    int b = blockIdx.z;
    int i0w = blockIdx.x * 64 + wave * 16;

    // stage wo[0..256)[0..128) -> f16 LDS (each thread: 1 full row)
    {
        const float* src = wo + (size_t)t * HID;
        f16* d = wol + t * WROW;
#pragma unroll
        for (int j = 0; j < 16; j++) {
            float4 a = *(const float4*)(src + j * 8);
            float4 bq = *(const float4*)(src + j * 8 + 4);
            f16x8 s;
            s[0] = (f16)a.x; s[1] = (f16)a.y; s[2] = (f16)a.z; s[3] = (f16)a.w;
            s[4] = (f16)bq.x; s[5] = (f16)bq.y; s[6] = (f16)bq.z; s[7] = (f16)bq.w;
            *(f16x8*)(d + j * 8) = s;
        }
    }
    __syncthreads();

    int i = i0w + col;               // this lane's A-row
    // per-lane inverse denominators for all 4 heads (matches combine: seq
    // adds over s, then rcpf)
    float invl[4];
#pragma unroll
    for (int h = 0; h < 4; h++) {
        float l = 0.f;
#pragma unroll
        for (int s = 0; s < NS; s++)
            l += lp[(size_t)(s * 16 + b * 4 + h) * NN + i];
        invl[h] = __builtin_amdgcn_rcpf(l);
    }

    const f32x4 z = {0.f, 0.f, 0.f, 0.f};
    f32x4 c[16];
#pragma unroll
    for (int ot = 0; ot < 16; ot++) c[ot] = z;

#pragma unroll
    for (int k0 = 0; k0 < HID; k0 += 32) {
        int h = k0 >> 5;
        f32x4 accA = z, accB = z;
#pragma unroll
        for (int s = 0; s < NS; s++) {
            const float* src = op + ((size_t)(s * 16 + b * 4 + h) * NN + i) * 32 + quad * 8;
            accA += *(const f32x4*)(src);
            accB += *(const f32x4*)(src + 4);
        }
        float iv = invl[h];
        f16x8 a0;
        a0[0] = (f16)(accA[0] * iv); a0[1] = (f16)(accA[1] * iv);
        a0[2] = (f16)(accA[2] * iv); a0[3] = (f16)(accA[3] * iv);
        a0[4] = (f16)(accB[0] * iv); a0[5] = (f16)(accB[1] * iv);
        a0[6] = (f16)(accB[2] * iv); a0[7] = (f16)(accB[3] * iv);
#pragma unroll
        for (int ot = 0; ot < 16; ot++) {
            f16x8 bf = *(const f16x8*)(wol + (size_t)(ot * 16 + col) * WROW + k0 + quad * 8);
            c[ot] = __builtin_amdgcn_mfma_f32_16x16x32_f16(a0, bf, c[ot], 0, 0, 0);
        }
    }

#pragma unroll
    for (int ot = 0; ot < 16; ot++) {
        int o = ot * 16 + col;
        float bias = bo[o];
        int ii = i0w + quad * 4;
        float4 st = {c[ot][0] + bias, c[ot][1] + bias,
                     c[ot][2] + bias, c[ot][3] + bias};
        *(float4*)(out + ((size_t)b * CC + o) * NN + ii) = st;
    }
}

// ---------------- kernel 3-fallback: output projection for SPLIT=1 ---------
__global__ __launch_bounds__(256, 4) void out_mfma(const f16* __restrict__ att16,
                                                   const float* __restrict__ wo,
                                                   const float* __restrict__ bo,
                                                   float* __restrict__ out) {
    __shared__ __align__(16) f16 wol[64 * WROW];
    int t = threadIdx.x;
    int wave = t >> 6, lane = t & 63;
    int quad = lane >> 4, col = lane & 15;
    int b = blockIdx.z;
    int i0w = blockIdx.x * 64 + wave * 16;
    int o0 = blockIdx.y * 64;
    const f16* ab = att16 + (size_t)b * NN * HID;

    {
        int row = t >> 2;            // 0..63
        int kq = (t & 3) * 32;       // 0,32,64,96
        const float* src = wo + (size_t)(o0 + row) * HID + kq;
        f16* d = wol + row * WROW + kq;
#pragma unroll
        for (int j = 0; j < 4; j++) {
            float4 a = *(const float4*)(src + j * 8);
            float4 bq = *(const float4*)(src + j * 8 + 4);
            f16x8 s;
            s[0] = (f16)a.x; s[1] = (f16)a.y; s[2] = (f16)a.z; s[3] = (f16)a.w;
            s[4] = (f16)bq.x; s[5] = (f16)bq.y; s[6] = (f16)bq.z; s[7] = (f16)bq.w;
            *(f16x8*)(d + j * 8) = s;
        }
    }
    __syncthreads();

    const f32x4 z = {0.f, 0.f, 0.f, 0.f};
    f32x4 c[4];
#pragma unroll
    for (int ot = 0; ot < 4; ot++) c[ot] = z;

#pragma unroll
    for (int k0 = 0; k0 < HID; k0 += 32) {
        f16x8 a0 = *(const f16x8*)(ab + (size_t)(i0w + col) * HID + k0 + quad * 8);
#pragma unroll
        for (int ot = 0; ot < 4; ot++) {
            f16x8 bf = *(const f16x8*)(wol + (size_t)(ot * 16 + col) * WROW + k0 + quad * 8);
            c[ot] = __builtin_amdgcn_mfma_f32_16x16x32_f16(a0, bf, c[ot], 0, 0, 0);
        }
    }

#pragma unroll
    for (int ot = 0; ot < 4; ot++) {
        int o = o0 + ot * 16 + col;
        float bias = bo[o];
        int i = i0w + quad * 4;
        float4 st = {c[ot][0] + bias, c[ot][1] + bias,
                     c[ot][2] + bias, c[ot][3] + bias};
        *(float4*)(out + ((size_t)b * CC + o) * NN + i) = st;
    }
}

extern "C" void kernel_launch(void* const* d_in, const int* in_sizes, int n_in,
                              void* d_out, int out_size, void* d_ws, size_t ws_size,
                              hipStream_t stream) {
    const float* x     = (const float*)d_in[0];
    const float* w_qkv = (const float*)d_in[1];
    const float* w_out = (const float*)d_in[2];
    const float* b_out = (const float*)d_in[3];
    float* out = (float*)d_out;

    char* ws = (char*)d_ws;
    f16* qh    = (f16*)(ws);                        // 4 MB
    f16* kh    = (f16*)(ws + (4u << 20));           // 4 MB
    f16* vh    = (f16*)(ws + (8u << 20));           // 4 MB
    f16* att16 = (f16*)(ws + (12u << 20));          // 4 MB (SPLIT=1 path only)

    qkv_mega<<<dim3(NN / 32, 3, BB), 256, 0, stream>>>(x, w_qkv, qh, kh, vh);

    if (ws_size >= (50ull << 20)) {
        // SPLIT=4: op 32 MB @16, lp 1 MB @48; attn grid 1024 (R8 config)
        float* op = (float*)(ws + (16ull << 20));
        float* lp = (float*)(ws + (48ull << 20));
        attn_mfma<4><<<dim3(1024), 256, 0, stream>>>(qh, kh, vh, op, lp, att16);
        out_fused<4><<<dim3(NN / 64, 1, BB), 256, 0, stream>>>(op, lp, w_out, b_out, out);
    } else if (ws_size >= (33ull << 20)) {
        // SPLIT=2: op 16 MB @16, lp 0.5 MB @32
        float* op = (float*)(ws + (16ull << 20));
        float* lp = (float*)(ws + (32ull << 20));
        attn_mfma<2><<<dim3(512), 256, 0, stream>>>(qh, kh, vh, op, lp, att16);
        out_fused<2><<<dim3(NN / 64, 1, BB), 256, 0, stream>>>(op, lp, w_out, b_out, out);
    } else {
        attn_mfma<1><<<dim3(256), 256, 0, stream>>>(qh, kh, vh, nullptr, nullptr, att16);
        out_mfma<<<dim3(NN / 64, CC / 64, BB), 256, 0, stream>>>(att16, w_out, b_out, out);
    }
}